// Round 4
// baseline (964.175 us; speedup 1.0000x reference)
//
#include <hip/hip_runtime.h>
#include <hip/hip_fp16.h>

#define N_NODES 100000
#define N_EDGES 500000
#define M_PAD   100096   // 782 * 128
#define N3      300000   // 3 * N_NODES (node-major, etype-minor keys)
#define NPB     512      // nodes per bucket (power of 2)
#define NBUK    196      // ceil(N_NODES / NPB)
#define KEYS_B  1536     // NPB * 3 keys per bucket
#define BCAP    12288    // bucket capacity (mean fill 7680, sigma 87)
#define CH_A    8192     // edges per bucketA block
#define NBLK_A  184      // ceil(3*N_EDGES / CH_A)
#define NWAVES  8192     // agg waves (2048 blocks x 4)

using f32x4  = __attribute__((ext_vector_type(4))) float;
using bf16x8 = __attribute__((ext_vector_type(8))) __bf16;

__device__ __forceinline__ ushort f2bf(float f) {
  union { float f; unsigned u; } v; v.f = f;
  unsigned r = v.u + 0x7fffu + ((v.u >> 16) & 1u);   // RNE
  return (ushort)(r >> 16);
}
__device__ __forceinline__ float bf2f(ushort b) {
  union { unsigned u; float f; } v; v.u = ((unsigned)b) << 16;
  return v.f;
}

// ---------------------------------------------------------------------------
// Conversions
// ---------------------------------------------------------------------------
__global__ __launch_bounds__(256) void cvt_x_kernel(const float* __restrict__ x,
                                                    ushort* __restrict__ h) {
  const size_t i = (size_t)blockIdx.x * 256 + threadIdx.x;  // float4 index
  ushort4 o;
  if (i < (size_t)N_NODES * 64) {
    const float4 v = ((const float4*)x)[i];
    o.x = f2bf(v.x); o.y = f2bf(v.y); o.z = f2bf(v.z); o.w = f2bf(v.w);
  } else {
    o.x = 0; o.y = 0; o.z = 0; o.w = 0;   // zero pad rows -> zero feat rows
  }
  ((ushort4*)h)[i] = o;
}

// W [le][k][n] fp32 -> Wt [le][n][k] bf16
__global__ __launch_bounds__(256) void cvt_w_kernel(const float* __restrict__ W,
                                                    ushort* __restrict__ Wt) {
  const int i = blockIdx.x * 256 + threadIdx.x;       // 6*65536
  const int le = i >> 16, r = i & 65535, nn = r >> 8, kk = r & 255;
  Wt[i] = f2bf(W[(le << 16) | (kk << 8) | nn]);
}

// W_out [256][349] -> Wto [384][256] bf16 transposed, zero-padded cols
__global__ __launch_bounds__(256) void cvt_wout_kernel(const float* __restrict__ Wo,
                                                       ushort* __restrict__ Wto) {
  const int i = blockIdx.x * 256 + threadIdx.x;       // 384*256
  const int nn = i >> 8, kk = i & 255;
  Wto[i] = f2bf(nn < 349 ? Wo[kk * 349 + nn] : 0.f);
}

// ---------------------------------------------------------------------------
// Atomic-light CSR build, grouped by (dst node, etype).
// Phase A: LDS-counted bucket scatter (bucket = dst>>9), one global atomic
// per (block,bucket) to reserve ranges; packed 4B records key<<19|srcid.
// Phase B: per-bucket LDS histogram + scan -> rowp3 + coalesced-window srcid.
// ---------------------------------------------------------------------------
__global__ __launch_bounds__(256) void zero_gcnt_kernel(int* __restrict__ gcnt) {
  const int i = threadIdx.x;
  if (i < NBUK) gcnt[i] = 0;
}

__global__ __launch_bounds__(256) void bucketA_kernel(const int* __restrict__ src,
                                                      const int* __restrict__ dst,
                                                      int* __restrict__ gcnt,
                                                      uint* __restrict__ barr) {
  __shared__ int cnt[NBUK];
  __shared__ int ofs[NBUK];
  const int t = threadIdx.x;
  const int base = blockIdx.x * CH_A;
  const int lim = (3 * N_EDGES - base < CH_A) ? (3 * N_EDGES - base) : CH_A;
  for (int b = t; b < NBUK; b += 256) cnt[b] = 0;
  __syncthreads();
  for (int k = t; k < lim; k += 256) {
    const int d = dst[base + k];
    atomicAdd(&cnt[d >> 9], 1);
  }
  __syncthreads();
  if (t < NBUK) {
    ofs[t] = atomicAdd(&gcnt[t], cnt[t]);
    cnt[t] = 0;
  }
  __syncthreads();
  for (int k = t; k < lim; k += 256) {
    const int i = base + k;
    const int d = dst[i];
    const int et = (i >= 2 * N_EDGES) ? 2 : ((i >= N_EDGES) ? 1 : 0);
    const uint key = (uint)((d & (NPB - 1)) * 3 + et);
    const uint sid = (uint)(et * M_PAD + src[i]);
    const int buk = d >> 9;
    int pos = ofs[buk] + atomicAdd(&cnt[buk], 1);
    if (pos < BCAP)
      barr[(size_t)buk * BCAP + pos] = (key << 19) | sid;
  }
}

__global__ __launch_bounds__(256) void scan196_kernel(const int* __restrict__ gcnt,
                                                      int* __restrict__ bbase,
                                                      int* __restrict__ rowp3) {
  __shared__ int sm[256];
  const int t = threadIdx.x;
  const int v = (t < NBUK) ? gcnt[t] : 0;
  sm[t] = v; __syncthreads();
  for (int off = 1; off < 256; off <<= 1) {
    const int x = (t >= off) ? sm[t - off] : 0;
    __syncthreads();
    sm[t] += x;
    __syncthreads();
  }
  if (t < NBUK) bbase[t] = sm[t] - v;   // exclusive
  if (t == 0) rowp3[N3] = 3 * N_EDGES;
}

__global__ __launch_bounds__(256) void csrB_kernel(const uint* __restrict__ barr,
                                                   const int* __restrict__ gcnt,
                                                   const int* __restrict__ bbase,
                                                   int* __restrict__ rowp3,
                                                   uint* __restrict__ srcid) {
  __shared__ int hist[KEYS_B];
  __shared__ int excl[KEYS_B];
  __shared__ int tsum[256];
  const int b = blockIdx.x, t = threadIdx.x;
  const int n = gcnt[b] < BCAP ? gcnt[b] : BCAP;
  const int cbase = bbase[b];
  const uint* ba = barr + (size_t)b * BCAP;
  for (int k = t; k < KEYS_B; k += 256) hist[k] = 0;
  __syncthreads();
  for (int r = t; r < n; r += 256) atomicAdd(&hist[ba[r] >> 19], 1);
  __syncthreads();
  // 256-thread scan over 1536 bins: thread t owns bins [6t, 6t+6)
  int loc[6];
  int s = 0;
#pragma unroll
  for (int j = 0; j < 6; ++j) { loc[j] = s; s += hist[t * 6 + j]; }
  tsum[t] = s; __syncthreads();
  for (int off = 1; off < 256; off <<= 1) {
    const int x = (t >= off) ? tsum[t - off] : 0;
    __syncthreads();
    tsum[t] += x;
    __syncthreads();
  }
  const int tbase = tsum[t] - s;    // exclusive over threads
#pragma unroll
  for (int j = 0; j < 6; ++j) excl[t * 6 + j] = tbase + loc[j];
  __syncthreads();
  // write rowp3 (global key id = b*KEYS_B + k = node*3 + et), reset cursors
  const int nrem = (N_NODES - b * NPB) * 3;
  const int kmax = (nrem < KEYS_B) ? nrem : KEYS_B;
  for (int k = t; k < KEYS_B; k += 256) {
    if (k < kmax) rowp3[b * KEYS_B + k] = cbase + excl[k];
    hist[k] = 0;
  }
  __syncthreads();
  for (int r = t; r < n; r += 256) {
    const uint rec = ba[r];
    const int key = (int)(rec >> 19);
    const int pos = excl[key] + atomicAdd(&hist[key], 1);
    srcid[cbase + pos] = rec & 0x7FFFFu;
  }
}

// ---------------------------------------------------------------------------
// Edge-balanced wave partition: wbeg[w] = first node whose edge-start is
// >= w * (3E / NWAVES). Waves get ~183 edges each (+- one node's degree).
// ---------------------------------------------------------------------------
__global__ __launch_bounds__(256) void bounds_kernel(const int* __restrict__ rowp3,
                                                     int* __restrict__ wbeg) {
  const int w = blockIdx.x * 256 + threadIdx.x;
  if (w > NWAVES) return;
  if (w == 0)      { wbeg[0] = 0;            return; }
  if (w == NWAVES) { wbeg[NWAVES] = N_NODES; return; }
  const int target = (int)(((long long)w * (3LL * N_EDGES)) >> 13);
  int lo = 0, hi = N_NODES;
  while (lo < hi) {
    const int mid = (lo + hi) >> 1;
    if (rowp3[mid * 3] < target) lo = mid + 1; else hi = mid;
  }
  wbeg[w] = lo;
}

// ---------------------------------------------------------------------------
// Fused feat GEMM: 128x128 tile for all 3 etypes, shared A tile; epilogue
// writes feat (bf16) and el/er (pitch M_PAD) via in-register head-dots.
// ---------------------------------------------------------------------------
__global__ __launch_bounds__(256, 2) void gemm_feat_fused(
    const ushort* __restrict__ A, const ushort* __restrict__ WtL,
    ushort* __restrict__ feat, const float* __restrict__ attn_l,
    const float* __restrict__ attn_r, float* __restrict__ el,
    float* __restrict__ er, int layer) {
  __shared__ ushort As[128 * 64];
  __shared__ ushort Bs[3 * 128 * 64];
  const int t = threadIdx.x;
  const int lane = t & 63;
  const int wave = t >> 6;
  const int wm = (wave >> 1) << 6;
  const int wn = (wave & 1) << 6;
  const int quad = lane >> 4;
  const int ln = lane & 15;
  const size_t m0 = (size_t)blockIdx.x * 128;
  const size_t n0 = (size_t)blockIdx.y * 128;

  f32x4 acc[3][4][4];
#pragma unroll
  for (int e = 0; e < 3; ++e)
#pragma unroll
    for (int x = 0; x < 4; ++x)
#pragma unroll
      for (int y = 0; y < 4; ++y)
        acc[e][x][y] = (f32x4){0.f, 0.f, 0.f, 0.f};

  for (int k0 = 0; k0 < 256; k0 += 64) {
    __syncthreads();
#pragma unroll
    for (int i = 0; i < 4; ++i) {
      const int f = i * 256 + t;
      const int row = f >> 3;
      const int cl = (f & 7) ^ (row & 7);                 // global-side swizzle
      const int ldsbase = (i * 256 + (t & ~63)) << 3;     // wave-uniform, ushort idx
      __builtin_amdgcn_global_load_lds(
          (const __attribute__((address_space(1))) void*)(A + (m0 + row) * 256 + k0 + cl * 8),
          (__attribute__((address_space(3))) void*)(As + ldsbase), 16, 0, 0);
#pragma unroll
      for (int e = 0; e < 3; ++e)
        __builtin_amdgcn_global_load_lds(
            (const __attribute__((address_space(1))) void*)(WtL + (e << 16) + (n0 + row) * 256 + k0 + cl * 8),
            (__attribute__((address_space(3))) void*)(Bs + e * 8192 + ldsbase), 16, 0, 0);
    }
    __syncthreads();
#pragma unroll
    for (int s = 0; s < 2; ++s) {
      const int cl = s * 4 + quad;
      bf16x8 af[4];
#pragma unroll
      for (int x = 0; x < 4; ++x) {
        const int mm = wm + x * 16 + ln;
        af[x] = *(const bf16x8*)(As + mm * 64 + ((cl ^ (mm & 7)) << 3));
      }
#pragma unroll
      for (int e = 0; e < 3; ++e) {
        bf16x8 bfr[4];
#pragma unroll
        for (int y = 0; y < 4; ++y) {
          const int nn = wn + y * 16 + ln;
          bfr[y] = *(const bf16x8*)(Bs + e * 8192 + nn * 64 + ((cl ^ (nn & 7)) << 3));
        }
#pragma unroll
        for (int x = 0; x < 4; ++x)
#pragma unroll
          for (int y = 0; y < 4; ++y)
            acc[e][x][y] = __builtin_amdgcn_mfma_f32_16x16x32_bf16(bfr[y], af[x], acc[e][x][y], 0, 0, 0);
      }
    }
  }

  const int h = (int)(n0 + wn) >> 6;                      // this wave's head
#pragma unroll
  for (int e = 0; e < 3; ++e) {
    ushort* C = feat + (size_t)e * M_PAD * 256;
#pragma unroll
    for (int x = 0; x < 4; ++x) {
      const size_t m = m0 + wm + x * 16 + ln;
#pragma unroll
      for (int y = 0; y < 4; ++y) {
        const size_t n = n0 + wn + y * 16 + quad * 4;
        ushort4 o;
        o.x = f2bf(acc[e][x][y][0]); o.y = f2bf(acc[e][x][y][1]);
        o.z = f2bf(acc[e][x][y][2]); o.w = f2bf(acc[e][x][y][3]);
        *(ushort4*)(C + m * 256 + n) = o;
      }
    }
    const float* al = attn_l + (((layer * 3 + e) * 4 + h) << 6);
    const float* ar = attn_r + (((layer * 3 + e) * 4 + h) << 6);
    float4 alv[4], arv[4];
#pragma unroll
    for (int y = 0; y < 4; ++y) {
      alv[y] = *(const float4*)(al + y * 16 + quad * 4);
      arv[y] = *(const float4*)(ar + y * 16 + quad * 4);
    }
#pragma unroll
    for (int x = 0; x < 4; ++x) {
      float pl = 0.f, pr = 0.f;
#pragma unroll
      for (int y = 0; y < 4; ++y) {
        pl += acc[e][x][y][0] * alv[y].x + acc[e][x][y][1] * alv[y].y +
              acc[e][x][y][2] * alv[y].z + acc[e][x][y][3] * alv[y].w;
        pr += acc[e][x][y][0] * arv[y].x + acc[e][x][y][1] * arv[y].y +
              acc[e][x][y][2] * arv[y].z + acc[e][x][y][3] * arv[y].w;
      }
      pl += __shfl_xor(pl, 16); pl += __shfl_xor(pl, 32);
      pr += __shfl_xor(pr, 16); pr += __shfl_xor(pr, 32);
      const int m = (int)m0 + wm + x * 16 + ln;
      if (quad == 0 && m < N_NODES) {
        el[((size_t)e * M_PAD + m) * 4 + h] = pl;
        er[((size_t)e * M_PAD + m) * 4 + h] = pr;
      }
    }
  }
}

// ---------------------------------------------------------------------------
// Final classifier GEMM (fp32 out + bias, guarded).
// ---------------------------------------------------------------------------
__global__ __launch_bounds__(256) void gemm128(const ushort* __restrict__ A,
                                               const ushort* __restrict__ Bt,
                                               float* __restrict__ C,
                                               const float* __restrict__ obias,
                                               int ldc, int nmax, int mmax) {
  __shared__ ushort As[128 * 64];
  __shared__ ushort Bs[128 * 64];
  const int t = threadIdx.x;
  const int lane = t & 63;
  const int wave = t >> 6;
  const int wm = (wave >> 1) << 6;
  const int wn = (wave & 1) << 6;
  const int quad = lane >> 4;
  const int ln = lane & 15;
  const size_t m0 = (size_t)blockIdx.x * 128;
  const size_t n0 = (size_t)blockIdx.y * 128;

  f32x4 acc[4][4];
#pragma unroll
  for (int x = 0; x < 4; ++x)
#pragma unroll
    for (int y = 0; y < 4; ++y)
      acc[x][y] = (f32x4){0.f, 0.f, 0.f, 0.f};

  for (int k0 = 0; k0 < 256; k0 += 64) {
    __syncthreads();
#pragma unroll
    for (int i = 0; i < 4; ++i) {
      const int f = i * 256 + t;
      const int row = f >> 3;
      const int cl = (f & 7) ^ (row & 7);
      const int ldsbase = (i * 256 + (t & ~63)) << 3;
      __builtin_amdgcn_global_load_lds(
          (const __attribute__((address_space(1))) void*)(A + (m0 + row) * 256 + k0 + cl * 8),
          (__attribute__((address_space(3))) void*)(As + ldsbase), 16, 0, 0);
      __builtin_amdgcn_global_load_lds(
          (const __attribute__((address_space(1))) void*)(Bt + (n0 + row) * 256 + k0 + cl * 8),
          (__attribute__((address_space(3))) void*)(Bs + ldsbase), 16, 0, 0);
    }
    __syncthreads();
#pragma unroll
    for (int s = 0; s < 2; ++s) {
      bf16x8 af[4], bfr[4];
      const int cl = s * 4 + quad;
#pragma unroll
      for (int x = 0; x < 4; ++x) {
        const int mm = wm + x * 16 + ln;
        af[x] = *(const bf16x8*)(As + mm * 64 + ((cl ^ (mm & 7)) << 3));
        const int nn = wn + x * 16 + ln;
        bfr[x] = *(const bf16x8*)(Bs + nn * 64 + ((cl ^ (nn & 7)) << 3));
      }
#pragma unroll
      for (int x = 0; x < 4; ++x)
#pragma unroll
        for (int y = 0; y < 4; ++y)
          acc[x][y] = __builtin_amdgcn_mfma_f32_16x16x32_bf16(bfr[y], af[x], acc[x][y], 0, 0, 0);
    }
  }

#pragma unroll
  for (int x = 0; x < 4; ++x) {
    const int m = (int)m0 + wm + x * 16 + ln;
    if (m < mmax) {
#pragma unroll
      for (int y = 0; y < 4; ++y) {
        const int n = (int)n0 + wn + y * 16 + quad * 4;
#pragma unroll
        for (int r = 0; r < 4; ++r)
          if (n + r < nmax)
            C[(size_t)m * ldc + n + r] = acc[x][y][r] + obias[n + r];
      }
    }
  }
}

// ---------------------------------------------------------------------------
// Fused aggregation: per etype-segment in-register softmax + weighted gather.
// w computed from el/er on the fly (no wcsr pass). All CSR/index loads are
// wave-uniform -> scalar; w is quad-uniform so den needs no cross-lane
// reduce. Edge-balanced node ranges from wbeg.
// ---------------------------------------------------------------------------
__global__ __launch_bounds__(256) void agg_kernel(const ushort* __restrict__ feat,
                                                  const int* __restrict__ rowp3,
                                                  const uint* __restrict__ srcid,
                                                  const float* __restrict__ el,
                                                  const float* __restrict__ er,
                                                  const float* __restrict__ bias,
                                                  const int* __restrict__ wbeg,
                                                  ushort* __restrict__ hout,
                                                  int layer, int do_relu) {
  const int wid  = __builtin_amdgcn_readfirstlane(
                     (int)(blockIdx.x * 4 + (threadIdx.x >> 6)));
  const int lane = threadIdx.x & 63;
  const int quad = lane >> 4;                 // head
  const int f8   = lane << 3;                 // byte offset into 512B feat row
  const float* bl = bias + layer * 768 + (lane << 2);
  const float b0 = bl[0] + bl[256] + bl[512];
  const float b1 = bl[1] + bl[257] + bl[513];
  const float b2 = bl[2] + bl[258] + bl[514];
  const float b3 = bl[3] + bl[259] + bl[515];
  const char* fb = (const char*)feat;
  const int nbeg = wbeg[wid];
  const int nend = wbeg[wid + 1];
  for (int n = nbeg; n < nend; ++n) {
    float a0 = b0, a1 = b1, a2 = b2, a3 = b3;
#pragma unroll
    for (int et = 0; et < 3; ++et) {
      const int b = rowp3[n * 3 + et];
      const int e = rowp3[n * 3 + et + 1];
      if (e == b) continue;
      const float erh = er[(((size_t)et * M_PAD + n) << 2) + quad];
      const int last = e - 1;
      float l0 = 0.f, l1 = 0.f, l2 = 0.f, l3 = 0.f, den = 0.f;
      for (int i = b; i < e; i += 8) {
        int idx[8];
#pragma unroll
        for (int j = 0; j < 8; ++j)
          idx[j] = (i + j < last) ? (i + j) : last;   // clamp: always valid
        uint sd[8];
#pragma unroll
        for (int j = 0; j < 8; ++j)
          sd[j] = srcid[idx[j]];
        float zl[8];
#pragma unroll
        for (int j = 0; j < 8; ++j)
          zl[j] = el[((size_t)sd[j] << 2) + quad];
        uint2 fv[8];
#pragma unroll
        for (int j = 0; j < 8; ++j)
          fv[j] = *(const uint2*)(fb + ((size_t)sd[j] << 9) + f8);
        float wj[8];
#pragma unroll
        for (int j = 0; j < 8; ++j) {
          float z = zl[j] + erh;
          z = (z > 0.f) ? z : 0.2f * z;
          wj[j] = (i + j <= last) ? __expf(z) : 0.f;  // branchless remainder
        }
#pragma unroll
        for (int j = 0; j < 8; ++j) {
          union { uint u; float f; } c0, c1, c2, c3;
          c0.u = fv[j].x << 16;
          c1.u = fv[j].x & 0xffff0000u;
          c2.u = fv[j].y << 16;
          c3.u = fv[j].y & 0xffff0000u;
          den += wj[j];
          l0 += wj[j] * c0.f;
          l1 += wj[j] * c1.f;
          l2 += wj[j] * c2.f;
          l3 += wj[j] * c3.f;
        }
      }
      const float inv = __builtin_amdgcn_rcpf(den);
      a0 += l0 * inv; a1 += l1 * inv; a2 += l2 * inv; a3 += l3 * inv;
    }
    if (do_relu) {
      a0 = fmaxf(a0, 0.f); a1 = fmaxf(a1, 0.f);
      a2 = fmaxf(a2, 0.f); a3 = fmaxf(a3, 0.f);
    }
    ushort4 o;
    o.x = f2bf(a0); o.y = f2bf(a1); o.z = f2bf(a2); o.w = f2bf(a3);
    *(ushort4*)(hout + (size_t)n * 256 + (lane << 2)) = o;
  }
}

// ---------------------------------------------------------------------------
extern "C" void kernel_launch(void* const* d_in, const int* in_sizes, int n_in,
                              void* d_out, int out_size, void* d_ws, size_t ws_size,
                              hipStream_t stream) {
  const float* x      = (const float*)d_in[0];
  const float* W      = (const float*)d_in[1];
  const float* attn_l = (const float*)d_in[2];
  const float* attn_r = (const float*)d_in[3];
  const float* bias   = (const float*)d_in[4];
  const float* W_out  = (const float*)d_in[5];
  const float* b_out  = (const float*)d_in[6];
  const int*   src    = (const int*)d_in[7];
  const int*   dst    = (const int*)d_in[8];

  char* p = (char*)d_ws;
  auto carve = [&](size_t bytes) {
    char* r = p;
    p += (bytes + 255) & ~(size_t)255;
    return r;
  };
  ushort* h_bf  = (ushort*)carve((size_t)M_PAD * 256 * 2);        //  51.2 MB
  ushort* feat  = (ushort*)carve((size_t)3 * M_PAD * 256 * 2);    // 153.7 MB
  ushort* Wt    = (ushort*)carve((size_t)6 * 65536 * 2);
  ushort* Wto   = (ushort*)carve((size_t)384 * 256 * 2);
  float*  el    = (float*)carve((size_t)3 * M_PAD * 4 * 4);       //   4.8 MB
  float*  er    = (float*)carve((size_t)3 * M_PAD * 4 * 4);       //   4.8 MB
  int*    rowp3 = (int*)carve((size_t)(N3 + 1) * 4);
  uint*   srcid = (uint*)carve((size_t)3 * N_EDGES * 4);          //   6 MB
  uint*   barr  = (uint*)carve((size_t)NBUK * BCAP * 4);          //   9.6 MB
  int*    gcnt  = (int*)carve((size_t)NBUK * 4);
  int*    bbase = (int*)carve((size_t)NBUK * 4);
  int*    wbeg  = (int*)carve((size_t)(NWAVES + 1) * 4);

  cvt_x_kernel<<<M_PAD * 64 / 256, 256, 0, stream>>>(x, h_bf);
  cvt_w_kernel<<<6 * 65536 / 256, 256, 0, stream>>>(W, Wt);
  cvt_wout_kernel<<<384 * 256 / 256, 256, 0, stream>>>(W_out, Wto);

  zero_gcnt_kernel<<<1, 256, 0, stream>>>(gcnt);
  bucketA_kernel<<<NBLK_A, 256, 0, stream>>>(src, dst, gcnt, barr);
  scan196_kernel<<<1, 256, 0, stream>>>(gcnt, bbase, rowp3);
  csrB_kernel<<<NBUK, 256, 0, stream>>>(barr, gcnt, bbase, rowp3, srcid);
  bounds_kernel<<<(NWAVES + 256) / 256, 256, 0, stream>>>(rowp3, wbeg);

  for (int l = 0; l < 2; ++l) {
    gemm_feat_fused<<<dim3(M_PAD / 128, 2), 256, 0, stream>>>(
        h_bf, Wt + (size_t)l * 3 * 65536, feat, attn_l, attn_r, el, er, l);
    agg_kernel<<<2048, 256, 0, stream>>>(feat, rowp3, srcid, el, er, bias,
                                         wbeg, h_bf, l, l == 0 ? 1 : 0);
  }
  gemm128<<<dim3(M_PAD / 128, 3), 256, 0, stream>>>(h_bf, Wto, (float*)d_out,
                                                    b_out, 349, 349, N_NODES);
}